// Round 10
// baseline (2136.115 us; speedup 1.0000x reference)
//
#include <hip/hip_runtime.h>

#define IMH 64
#define IMW 64
#define HWSZ 4096
#define BATCH 16
#define TSTEPS 16
#define PADW 66

typedef _Float16 half8 __attribute__((ext_vector_type(8)));
typedef _Float16 half4 __attribute__((ext_vector_type(4)));
typedef float floatx4 __attribute__((ext_vector_type(4)));
typedef int intx4 __attribute__((ext_vector_type(4)));

__device__ __forceinline__ float sigmoidf_(float x) { return 1.f / (1.f + __expf(-x)); }
__device__ __forceinline__ float tanhf_(float x) { return 1.f - 2.f / (1.f + __expf(2.f * x)); }

// Dense weight repack: wr[gt32][m][k32], m = (g*4+hg)*16 + i, out = g*64+hg*16+i.
// kg = c32*32+k (c32 = gt32/9) ; xmode: kg<64 -> ci=kg+1 (h), kg==64 -> ci=0 (x), else 0.
__global__ void repack_w(const float* __restrict__ w, _Float16* __restrict__ wr,
                         int ngt, int cin, int xmode) {
    int total = ngt * 8192;
    for (int idx = blockIdx.x * blockDim.x + threadIdx.x; idx < total;
         idx += gridDim.x * blockDim.x) {
        int k = idx & 31;
        int m = (idx >> 5) & 255;
        int gt = idx >> 13;
        int chunk = gt / 9, tap = gt - chunk * 9;
        int bidx = m >> 4, i = m & 15;
        int g = bidx >> 2, hg = bidx & 3;
        int out = g * 64 + hg * 16 + i;
        int kg = chunk * 32 + k;
        int ci = xmode ? (kg < 64 ? kg + 1 : (kg == 64 ? 0 : -1))
                       : (kg < cin ? kg : -1);
        float v = (ci >= 0) ? w[(out * cin + ci) * 9 + tap] : 0.f;
        wr[idx] = (_Float16)v;
    }
}

// Fused conv3x3 -> 4 gates -> LSTM update. f16 MFMA implicit GEMM.
// Block: 256 thr (4 waves = 4 hid-groups), TWO image rows x 64 cols: wave tile
// M=64 (4 gates x 16 hids) x N=128 (8 ni: 2 rows x 4 col-quarters). 512 blocks=2/CU.
// K-loop: 64-channel chunks (2 x 32-ch planes in LDS) -> per tap 2 k-slabs, 64 MFMAs
// between latency exposures; 2 barriers per 64-ch chunk (4/dispatch for layer1).
// Weights direct from L1/L2 (per-lane contiguous 16B). Per-wave TAP ROTATION
// (taps commute in the accumulation) desyncs the 4 waves' memory bursts after
// each barrier. LDS 5-slot (80B) pixel stride -> 2-way bank access (free).
// __launch_bounds__(256,2): ~128 VGPR of room for the compiler to hoist
// next-slab fragments across the MFMA block.
template<int NCHUNK, int XCHUNK>
__global__ __launch_bounds__(256, 2) void lstm_mfma_kernel(
    const _Float16* __restrict__ srcA,    // chunk 0 source (padded pixel-major h)
    const _Float16* __restrict__ srcB,    // chunk 1 source
    const float* __restrict__ xsrc,       // layer0 x_t (batch stride TSTEPS*HWSZ)
    _Float16* __restrict__ hpad,          // out h [B][66][66][64]
    float* __restrict__ cpix,             // in-place c [B][4096][64]
    const _Float16* __restrict__ wr,      // [NGT32][256][32] dense f16
    const float* __restrict__ bias)       // [256]
{
    __shared__ __align__(16) _Float16 act[2][10560];  // plane = 264 px x 5 slots x 16B

    const int tid = threadIdx.x;
    const int lane = tid & 63;
    const int n = lane & 15, q = lane >> 4;
    const int hg = tid >> 6;                 // wave = hid group 0..3
    const int rb = blockIdx.x;               // row pair 0..31
    const int b = blockIdx.y;
    const int toff = hg * 2;                 // per-wave tap rotation offset

    floatx4 acc[4][8];
    #pragma unroll
    for (int g = 0; g < 4; ++g)
        #pragma unroll
        for (int i = 0; i < 8; ++i) acc[g][i] = (floatx4){0.f, 0.f, 0.f, 0.f};

    #pragma unroll
    for (int chunk = 0; chunk < NCHUNK; ++chunk) {
        __syncthreads();                     // B1: prev chunk's act readers done
        if (chunk == XCHUNK) {
            // x chunk: plane0 slot0 = x, other slots zero; plane1 unused (1 slab)
            for (int t = tid; t < 1056; t += 256) {
                int pix = t >> 2, sl = t & 3;
                int r = pix / 66, cs = pix - r * 66;
                half8 hv;
                #pragma unroll
                for (int j = 0; j < 8; ++j) hv[j] = (_Float16)0.f;
                if (sl == 0) {
                    int gy = rb * 2 - 1 + r, gx = cs - 1;
                    if (gy >= 0 && gy < IMH && gx >= 0 && gx < IMW)
                        hv[0] = (_Float16)xsrc[(size_t)b * (TSTEPS * HWSZ) + gy * IMW + gx];
                }
                *(half8*)&act[0][(pix * 5 + sl) * 8] = hv;
            }
        } else {
            const _Float16* buf = (chunk == 0) ? srcA : srcB;
            // 4 halo rows x 66 cols x 64 ch = 2112 16B units (both planes)
            for (int t = tid; t < 2112; t += 256) {
                int kh = (t >= 1056);
                int u = t - kh * 1056;
                int pix = u >> 2, sl = u & 3;
                int r = pix / 66, cs = pix - r * 66;
                const _Float16* g = buf
                    + ((size_t)(b * PADW + rb * 2 + r) * PADW + cs) * 64
                    + kh * 32 + sl * 8;
                *(intx4*)&act[kh][(pix * 5 + sl) * 8] = *(const intx4*)g;
            }
        }
        __syncthreads();                     // B2: act writes visible
        constexpr int NSLAB_FULL = 2;
        const int nslab = (chunk == XCHUNK) ? 1 : NSLAB_FULL;
        #pragma unroll
        for (int tap = 0; tap < 9; ++tap) {
            int tr = tap + toff;
            if (tr >= 9) tr -= 9;            // rotated tap (accumulation commutes)
            const int dy = tr / 3, dx = tr - dy * 3;
            #pragma unroll
            for (int kh = 0; kh < 2; ++kh) {
                if (kh >= nslab) continue;
                const _Float16* wb = wr
                    + (size_t)((chunk * 2 + kh) * 9 + tr) * 8192
                    + (hg * 16 + n) * 32 + q * 8;
                half8 wfr[4];
                #pragma unroll
                for (int g = 0; g < 4; ++g)
                    wfr[g] = *(const half8*)(wb + g * 2048);
                half8 bfr[8];
                #pragma unroll
                for (int ni = 0; ni < 8; ++ni) {
                    int row = (ni >> 2) + dy;            // 0..3
                    int col = 16 * (ni & 3) + n + dx;    // 0..65
                    bfr[ni] = *(const half8*)&act[kh][((row * 66 + col) * 5 + q) * 8];
                }
                #pragma unroll
                for (int g = 0; g < 4; ++g)
                    #pragma unroll
                    for (int ni = 0; ni < 8; ++ni)
                        acc[g][ni] = __builtin_amdgcn_mfma_f32_16x16x32_f16(
                            wfr[g], bfr[ni], acc[g][ni], 0, 0, 0);
            }
        }
    }

    // Epilogue: lane holds gates for h = hg*16+q*4+r, pixel row rb*2+(ni>>2), col 16*(ni&3)+n
    const int hb = hg * 16 + q * 4;
    floatx4 bi = *(const floatx4*)&bias[hb];
    floatx4 bf = *(const floatx4*)&bias[64 + hb];
    floatx4 bo = *(const floatx4*)&bias[128 + hb];
    floatx4 bg = *(const floatx4*)&bias[192 + hb];
    #pragma unroll
    for (int ni = 0; ni < 8; ++ni) {
        int y = rb * 2 + (ni >> 2);
        int col = 16 * (ni & 3) + n;
        size_t cidx = ((size_t)b * HWSZ + y * IMW + col) * 64 + hb;
        floatx4 cold = *(const floatx4*)&cpix[cidx];
        floatx4 cnew;
        half4 hv;
        #pragma unroll
        for (int r = 0; r < 4; ++r) {
            float zi = acc[0][ni][r] + bi[r];
            float zf = acc[1][ni][r] + bf[r];
            float zo = acc[2][ni][r] + bo[r];
            float zg = acc[3][ni][r] + bg[r];
            float cn = fmaf(sigmoidf_(zf), cold[r], sigmoidf_(zi) * tanhf_(zg));
            cnew[r] = cn;
            hv[r] = (_Float16)(sigmoidf_(zo) * tanhf_(cn));
        }
        *(floatx4*)&cpix[cidx] = cnew;
        *(half4*)&hpad[((size_t)(b * PADW + y + 1) * PADW + col + 1) * 64 + hb] = hv;
    }
}

__global__ void head_kernel(const _Float16* __restrict__ h1pad,
                            const float* __restrict__ wh,
                            const float* __restrict__ bh,
                            float* __restrict__ out) {
    int nn = blockIdx.x * blockDim.x + threadIdx.x;  // 0..65535
    int b = nn >> 12, pp = nn & 4095;
    int y = pp >> 6, xc = pp & 63;
    const _Float16* base = h1pad + ((size_t)(b * PADW + y + 1) * PADW + xc + 1) * 64;
    float s = bh[0];
    #pragma unroll
    for (int h0 = 0; h0 < 64; h0 += 8) {
        half8 hv = *(const half8*)&base[h0];
        #pragma unroll
        for (int j = 0; j < 8; ++j) s = fmaf((float)hv[j], wh[h0 + j], s);
    }
    out[nn] = fmaxf(s, 0.f);
}

extern "C" void kernel_launch(void* const* d_in, const int* in_sizes, int n_in,
                              void* d_out, int out_size, void* d_ws, size_t ws_size,
                              hipStream_t stream) {
    const float* x  = (const float*)d_in[0];
    const float* w0 = (const float*)d_in[1];
    const float* b0 = (const float*)d_in[2];
    const float* w1 = (const float*)d_in[3];
    const float* b1 = (const float*)d_in[4];
    const float* wh = (const float*)d_in[5];
    const float* bh = (const float*)d_in[6];
    float* out = (float*)d_out;

    const size_t HPAD = (size_t)BATCH * PADW * PADW * 64;  // 4,460,544 halves
    const size_t CBUF = (size_t)BATCH * HWSZ * 64;         // 4,194,304 floats
    _Float16* hp  = (_Float16*)d_ws;
    _Float16* h0a = hp;
    _Float16* h0b = hp + HPAD;
    _Float16* h1a = hp + 2 * HPAD;
    _Float16* h1b = hp + 3 * HPAD;
    float* cbase = (float*)(hp + 4 * HPAD);
    float* c0 = cbase;
    float* c1 = cbase + CBUF;
    _Float16* wr0 = (_Float16*)(cbase + 2 * CBUF);   // 27*8192 halves
    _Float16* wr1 = wr0 + (size_t)27 * 8192;         // 36*8192 halves

    // zero h buffers (borders must stay 0) and c buffers
    hipMemsetAsync(d_ws, 0, 4 * HPAD * sizeof(_Float16) + 2 * CBUF * sizeof(float), stream);
    repack_w<<<864, 256, 0, stream>>>(w0, wr0, 27, 65, 1);
    repack_w<<<1152, 256, 0, stream>>>(w1, wr1, 36, 128, 0);

    _Float16* h0buf[2] = {h0a, h0b};
    _Float16* h1buf[2] = {h1a, h1b};
    dim3 grid(32, BATCH), block(256);                // 512 blocks = 2/CU
    for (int t = 0; t < TSTEPS; ++t) {
        int cur = t & 1, nxt = cur ^ 1;
        // layer0: chunk0 = h0 (64ch), chunk1 = x slab (32ch, 1 slab)
        lstm_mfma_kernel<2, 1><<<grid, block, 0, stream>>>(
            h0buf[cur], (const _Float16*)nullptr, x + (size_t)t * HWSZ,
            h0buf[nxt], c0, wr0, b0);
        // layer1: chunk0 = h0new (64ch), chunk1 = h1 (64ch)
        lstm_mfma_kernel<2, -1><<<grid, block, 0, stream>>>(
            h0buf[nxt], h1buf[cur], (const float*)nullptr,
            h1buf[nxt], c1, wr1, b1);
    }
    // t=15 wrote h1buf[0]
    head_kernel<<<256, 256, 0, stream>>>(h1buf[0], wh, bh, out);
}

// Round 11
// 1559.387 us; speedup vs baseline: 1.3698x; 1.3698x over previous
//
#include <hip/hip_runtime.h>

#define IMH 64
#define IMW 64
#define HWSZ 4096
#define BATCH 16
#define TSTEPS 16
#define PADW 66

typedef _Float16 half8 __attribute__((ext_vector_type(8)));
typedef _Float16 half4 __attribute__((ext_vector_type(4)));
typedef float floatx4 __attribute__((ext_vector_type(4)));
typedef int intx4 __attribute__((ext_vector_type(4)));

__device__ __forceinline__ float sigmoidf_(float x) { return 1.f / (1.f + __expf(-x)); }
__device__ __forceinline__ float tanhf_(float x) { return 1.f - 2.f / (1.f + __expf(2.f * x)); }

// layer1 weights: 36 slabs wr[gt][m][k32]; m=(g*4+hg)*16+i -> out=g*64+hg*16+i; ci=chunk*32+k.
__global__ void repack_w1(const float* __restrict__ w, _Float16* __restrict__ wr) {
    int total = 36 * 8192;
    for (int idx = blockIdx.x * blockDim.x + threadIdx.x; idx < total;
         idx += gridDim.x * blockDim.x) {
        int k = idx & 31;
        int m = (idx >> 5) & 255;
        int gt = idx >> 13;
        int chunk = gt / 9, tap = gt - chunk * 9;
        int g = m >> 6, hg = (m >> 4) & 3, i = m & 15;
        int out = g * 64 + hg * 16 + i;
        int ci = chunk * 32 + k;
        wr[idx] = (_Float16)w[(out * 128 + ci) * 9 + tap];
    }
}

// layer0 weights: 18 h-slabs (ci = chunk*32+k+1) + 1 x-slab (K-dim = tap: A[m][k]=w_x[out][k], k<9).
__global__ void repack_w0(const float* __restrict__ w, _Float16* __restrict__ wr) {
    int total = 19 * 8192;
    for (int idx = blockIdx.x * blockDim.x + threadIdx.x; idx < total;
         idx += gridDim.x * blockDim.x) {
        int k = idx & 31;
        int m = (idx >> 5) & 255;
        int gt = idx >> 13;
        int g = m >> 6, hg = (m >> 4) & 3, i = m & 15;
        int out = g * 64 + hg * 16 + i;
        float v = 0.f;
        if (gt < 18) {
            int chunk = gt / 9, tap = gt - chunk * 9;
            v = w[(out * 65 + (chunk * 32 + k + 1)) * 9 + tap];
        } else if (k < 9) {
            v = w[(out * 65 + 0) * 9 + k];   // x-plane, tap k
        }
        wr[idx] = (_Float16)v;
    }
}

// ---- shared device pieces (R8 block structure: 1 row x 64 cols, wave tile 64x64) ----

__device__ __forceinline__ void stage_h(const _Float16* __restrict__ buf, int halfsel,
                                        _Float16* __restrict__ act, int tid, int b, int rb) {
    // 3 halo rows x 66 cols x 32 ch -> 792 16B units; 5-slot (80B) pixel stride in LDS
    for (int t = tid; t < 792; t += 256) {
        int pix = t >> 2, sl = t & 3;
        int r = pix / 66, cs = pix - r * 66;
        const _Float16* g = buf
            + ((size_t)(b * PADW + rb + r) * PADW + cs) * 64 + halfsel * 32 + sl * 8;
        *(intx4*)&act[(pix * 5 + sl) * 8] = *(const intx4*)g;
    }
}

// NH = number of 32-ch h chunks; XS = append single x-slab (taps in K-dim)
template<int NH, bool XS>
__device__ __forceinline__ void lstm_body(
    const _Float16* __restrict__ srcA,    // h chunks 0-1
    const _Float16* __restrict__ srcB,    // h chunks 2-3
    const float* __restrict__ xsrc,       // layer0 x_t
    _Float16* __restrict__ hpad,          // out h [B][66][66][64]
    float* __restrict__ cpix,             // in-place c [B][4096][64]
    const _Float16* __restrict__ wr,      // [NH*9(+1)][256][32]
    const float* __restrict__ bias,       // [256]
    _Float16* __restrict__ act,           // LDS, 198*5*8 halves
    int tid, int rb, int b)
{
    const int lane = tid & 63;
    const int n = lane & 15, q = lane >> 4;
    const int hg = tid >> 6;

    floatx4 acc[4][4];
    #pragma unroll
    for (int g = 0; g < 4; ++g)
        #pragma unroll
        for (int i = 0; i < 4; ++i) acc[g][i] = (floatx4){0.f, 0.f, 0.f, 0.f};

    #pragma unroll
    for (int chunk = 0; chunk < NH; ++chunk) {
        __syncthreads();                     // prev act readers done
        stage_h((chunk < 2) ? srcA : srcB, chunk & 1, act, tid, b, rb);
        __syncthreads();                     // writes visible
        const _Float16* wbase = wr + (size_t)(chunk * 9) * 8192 + (hg * 16 + n) * 32 + q * 8;
        #pragma unroll
        for (int tap = 0; tap < 9; ++tap) {
            half8 wfr[4];
            #pragma unroll
            for (int g = 0; g < 4; ++g)
                wfr[g] = *(const half8*)(wbase + (size_t)tap * 8192 + g * 2048);
            const int dy = tap / 3, dx = tap - dy * 3;
            half8 bfr[4];
            #pragma unroll
            for (int ni = 0; ni < 4; ++ni) {
                int col = 16 * ni + n + dx;
                bfr[ni] = *(const half8*)&act[((dy * 66 + col) * 5 + q) * 8];
            }
            #pragma unroll
            for (int g = 0; g < 4; ++g)
                #pragma unroll
                for (int ni = 0; ni < 4; ++ni)
                    acc[g][ni] = __builtin_amdgcn_mfma_f32_16x16x32_f16(
                        wfr[g], bfr[ni], acc[g][ni], 0, 0, 0);
        }
    }

    if (XS) {
        // x-slab: B[k=tap][col] = x(rb-1+k/3, col-1+k%3), single K=32 slab (k>=9 zero)
        __syncthreads();
        {
            int pix = tid >> 2, sl = tid & 3;
            half8 hv;
            #pragma unroll
            for (int j = 0; j < 8; ++j) hv[j] = (_Float16)0.f;
            const float* xb = xsrc + (size_t)b * (TSTEPS * HWSZ);
            if (sl == 0) {
                #pragma unroll
                for (int j = 0; j < 8; ++j) {
                    int gy = rb - 1 + j / 3, gx = pix - 1 + j % 3;
                    if (gy >= 0 && gy < IMH && gx >= 0 && gx < IMW)
                        hv[j] = (_Float16)xb[gy * IMW + gx];
                }
            } else if (sl == 1) {
                int gy = rb + 1, gx = pix + 1;           // tap 8: dy=2,dx=2
                if (gy < IMH && gx < IMW)
                    hv[0] = (_Float16)xb[gy * IMW + gx];
            }
            *(half8*)&act[(pix * 5 + sl) * 8] = hv;
        }
        __syncthreads();
        const _Float16* wbase = wr + (size_t)(NH * 9) * 8192 + (hg * 16 + n) * 32 + q * 8;
        half8 wfr[4];
        #pragma unroll
        for (int g = 0; g < 4; ++g)
            wfr[g] = *(const half8*)(wbase + g * 2048);
        half8 bfr[4];
        #pragma unroll
        for (int ni = 0; ni < 4; ++ni)
            bfr[ni] = *(const half8*)&act[((16 * ni + n) * 5 + q) * 8];
        #pragma unroll
        for (int g = 0; g < 4; ++g)
            #pragma unroll
            for (int ni = 0; ni < 4; ++ni)
                acc[g][ni] = __builtin_amdgcn_mfma_f32_16x16x32_f16(
                    wfr[g], bfr[ni], acc[g][ni], 0, 0, 0);
    }

    // Epilogue: lane holds gates for h = hg*16+q*4+r, pixel row rb, col 16*ni+n
    const int hb = hg * 16 + q * 4;
    floatx4 bi = *(const floatx4*)&bias[hb];
    floatx4 bf = *(const floatx4*)&bias[64 + hb];
    floatx4 bo = *(const floatx4*)&bias[128 + hb];
    floatx4 bg = *(const floatx4*)&bias[192 + hb];
    #pragma unroll
    for (int ni = 0; ni < 4; ++ni) {
        int col = 16 * ni + n;
        size_t cidx = ((size_t)b * HWSZ + rb * IMW + col) * 64 + hb;
        floatx4 cold = *(const floatx4*)&cpix[cidx];
        floatx4 cnew;
        half4 hv;
        #pragma unroll
        for (int r = 0; r < 4; ++r) {
            float zi = acc[0][ni][r] + bi[r];
            float zf = acc[1][ni][r] + bf[r];
            float zo = acc[2][ni][r] + bo[r];
            float zg = acc[3][ni][r] + bg[r];
            float cn = fmaf(sigmoidf_(zf), cold[r], sigmoidf_(zi) * tanhf_(zg));
            cnew[r] = cn;
            hv[r] = (_Float16)(sigmoidf_(zo) * tanhf_(cn));
        }
        *(floatx4*)&cpix[cidx] = cnew;
        *(half4*)&hpad[((size_t)(b * PADW + rb + 1) * PADW + col + 1) * 64 + hb] = hv;
    }
}

// Merged dispatch: role 0 = layer1(t-1), role 1 = layer0(t). Roles are independent
// (both only READ h0_out(t-1); writes go to disjoint buffers). grid.z=2 runs both;
// grid.z=1 runs role_single only.
__global__ __launch_bounds__(256, 4) void fused_step(
    const _Float16* __restrict__ a1, const _Float16* __restrict__ b1,
    _Float16* __restrict__ h1o, float* __restrict__ c1p,
    const _Float16* __restrict__ w1r, const float* __restrict__ bias1,
    const _Float16* __restrict__ a0, const float* __restrict__ x0,
    _Float16* __restrict__ h0o, float* __restrict__ c0p,
    const _Float16* __restrict__ w0r, const float* __restrict__ bias0,
    int role_single)
{
    __shared__ __align__(16) _Float16 act[198 * 5 * 8];   // 15.8 KB
    const int tid = threadIdx.x;
    const int rb = blockIdx.x, b = blockIdx.y;
    const int role = (gridDim.z == 2) ? (int)blockIdx.z : role_single;
    if (role == 0)
        lstm_body<4, false>(a1, b1, nullptr, h1o, c1p, w1r, bias1, act, tid, rb, b);
    else
        lstm_body<2, true>(a0, nullptr, x0, h0o, c0p, w0r, bias0, act, tid, rb, b);
}

__global__ void head_kernel(const _Float16* __restrict__ h1pad,
                            const float* __restrict__ wh,
                            const float* __restrict__ bh,
                            float* __restrict__ out) {
    int nn = blockIdx.x * blockDim.x + threadIdx.x;  // 0..65535
    int b = nn >> 12, pp = nn & 4095;
    int y = pp >> 6, xc = pp & 63;
    const _Float16* base = h1pad + ((size_t)(b * PADW + y + 1) * PADW + xc + 1) * 64;
    float s = bh[0];
    #pragma unroll
    for (int h0 = 0; h0 < 64; h0 += 8) {
        half8 hv = *(const half8*)&base[h0];
        #pragma unroll
        for (int j = 0; j < 8; ++j) s = fmaf((float)hv[j], wh[h0 + j], s);
    }
    out[nn] = fmaxf(s, 0.f);
}

extern "C" void kernel_launch(void* const* d_in, const int* in_sizes, int n_in,
                              void* d_out, int out_size, void* d_ws, size_t ws_size,
                              hipStream_t stream) {
    const float* x  = (const float*)d_in[0];
    const float* w0 = (const float*)d_in[1];
    const float* b0 = (const float*)d_in[2];
    const float* w1 = (const float*)d_in[3];
    const float* b1 = (const float*)d_in[4];
    const float* wh = (const float*)d_in[5];
    const float* bh = (const float*)d_in[6];
    float* out = (float*)d_out;

    const size_t HPAD = (size_t)BATCH * PADW * PADW * 64;  // 4,460,544 halves
    const size_t CBUF = (size_t)BATCH * HWSZ * 64;         // 4,194,304 floats
    _Float16* hp  = (_Float16*)d_ws;
    _Float16* h0a = hp;
    _Float16* h0b = hp + HPAD;
    _Float16* h1a = hp + 2 * HPAD;
    _Float16* h1b = hp + 3 * HPAD;
    float* cbase = (float*)(hp + 4 * HPAD);
    float* c0 = cbase;
    float* c1 = cbase + CBUF;
    _Float16* wr0 = (_Float16*)(cbase + 2 * CBUF);   // 19*8192 halves
    _Float16* wr1 = wr0 + (size_t)19 * 8192;         // 36*8192 halves

    // zero h buffers (borders must stay 0) and c buffers — ws is re-poisoned each call
    hipMemsetAsync(d_ws, 0, 4 * HPAD * sizeof(_Float16) + 2 * CBUF * sizeof(float), stream);
    repack_w0<<<608, 256, 0, stream>>>(w0, wr0);
    repack_w1<<<1152, 256, 0, stream>>>(w1, wr1);

    _Float16* h0buf[2] = {h0a, h0b};
    _Float16* h1buf[2] = {h1a, h1b};
    dim3 block(256);

    // D0: layer0(t=0) only: reads h0buf[0] (zeros) + x(0) -> writes h0buf[1], c0
    fused_step<<<dim3(64, BATCH, 1), block, 0, stream>>>(
        nullptr, nullptr, nullptr, nullptr, nullptr, nullptr,
        h0buf[0], x, h0buf[1], c0, wr0, b0, 1);

    // steady: z=0 -> L1(t-1), z=1 -> L0(t); both read h0_out(t-1) = h0buf[t&1]
    for (int t = 1; t < TSTEPS; ++t) {
        fused_step<<<dim3(64, BATCH, 2), block, 0, stream>>>(
            h0buf[t & 1], h1buf[(t - 1) & 1], h1buf[t & 1], c1, wr1, b1,
            h0buf[t & 1], x + (size_t)t * HWSZ, h0buf[(t + 1) & 1], c0, wr0, b0, 0);
    }

    // final: layer1(t=15): reads h0buf[0], h1buf[1] -> writes h1buf[0]
    fused_step<<<dim3(64, BATCH, 1), block, 0, stream>>>(
        h0buf[0], h1buf[1], h1buf[0], c1, wr1, b1,
        nullptr, nullptr, nullptr, nullptr, nullptr, nullptr, 0);

    head_kernel<<<256, 256, 0, stream>>>(h1buf[0], wh, bh, out);
}